// Round 2
// baseline (644.211 us; speedup 1.0000x reference)
//
#include <hip/hip_runtime.h>

#define H  400
#define NB 16
#define CI 4
#define CO 32
#define NO (NB * CO)     // 512
#define NS 25            // strips per axis (H / 16)

// ---------------- K_rc: fused rows+cols over 16x16 squares ----------------
// Block = one (I,K) square of the HxH plane, all n, o, c.
//   rows[n,o,I+di] += sum_{c,dk} X[n,c,I+di,K+dk] * T[o,c,I+di,K+dk]
//   cols[n,o,K+dk] += sum_{c,di} X[n,c,I+di,K+dk] * T[o,c,I+di,K+dk]
// X read ONCE from HBM (41 MB total) -- no transpose kernel, no XT buffer.
// Thread owns (o = tid&31, n in {n2, n2+8}); X LDS reads are half-wave
// broadcasts (free), T reads are 4-way (float4-granular starts), partial
// stores are lane-consecutive (no = tid).
// Partials: rowsP[tk][i][no] (summed over 25 tk), colsP[ti][j][no] (over ti).
__global__ __launch_bounds__(256, 3) void k_rc(const float* __restrict__ x,
        const float* __restrict__ L,
        float* __restrict__ rowsP, float* __restrict__ colsP)
{
    __shared__ __align__(16) float Xs[NB][16][16];   // 16 KB  [n][di][dk]
    __shared__ __align__(16) float Ts[64][128];      // 32 KB  [di*4+qk][o*4+w]
    int b  = blockIdx.x;
    int ti = b / NS, tk = b % NS;
    int I = ti * 16, K = tk * 16;
    int tid = threadIdx.x;
    int o  = tid & 31;
    int n2 = tid >> 5;          // 0..7
    const float4* x4 = (const float4*)x;
    const float4* L4 = (const float4*)L;

    float ar0[16] = {}, ar1[16] = {}, ac0[16] = {}, ac1[16] = {};

    for (int c = 0; c < CI; ++c) {
        __syncthreads();        // protect Xs/Ts against previous iteration's readers
        // stage X square for all 16 n: 1024 float4, conflict-free b128 writes
        for (int e = tid; e < 1024; e += 256) {
            int q  = e & 3;
            int di = (e >> 2) & 15;
            int n  = e >> 6;
            ((float4*)Xs)[e] = x4[((size_t)(n * CI + c) * H + I + di) * 100 + tk * 4 + q];
        }
        // compute T[o][di][dk] = sum_r L[o,c,I+di,r]*L[o,c,K+dk,r]
        // thread covers its o and di in {2*n2, 2*n2+1}, all dk (L is L2-hot, RANK=4=1 float4)
        {
            const float4* Lrow = L4 + (size_t)(o * CI + c) * H;
            float4 Li0 = Lrow[I + 2 * n2];
            float4 Li1 = Lrow[I + 2 * n2 + 1];
            #pragma unroll
            for (int qk = 0; qk < 4; ++qk) {
                float4 t0, t1;
                #pragma unroll
                for (int w = 0; w < 4; ++w) {
                    float4 Lk = Lrow[K + qk * 4 + w];
                    ((float*)&t0)[w] = Li0.x * Lk.x + Li0.y * Lk.y + Li0.z * Lk.z + Li0.w * Lk.w;
                    ((float*)&t1)[w] = Li1.x * Lk.x + Li1.y * Lk.y + Li1.z * Lk.z + Li1.w * Lk.w;
                }
                *(float4*)&Ts[(2 * n2)     * 4 + qk][o * 4] = t0;
                *(float4*)&Ts[(2 * n2 + 1) * 4 + qk][o * 4] = t1;
            }
        }
        __syncthreads();
        // accumulate: per (di,qk): 3 b128 reads (2 broadcast X + 1 T), 16 FMA
        #pragma unroll
        for (int di = 0; di < 16; ++di) {
            #pragma unroll
            for (int qk = 0; qk < 4; ++qk) {
                float4 tv = *(const float4*)&Ts[di * 4 + qk][o * 4];
                float4 xa = ((const float4*)&Xs[n2][di][0])[qk];
                float4 xb = ((const float4*)&Xs[n2 + 8][di][0])[qk];
                ar0[di] += tv.x * xa.x + tv.y * xa.y + tv.z * xa.z + tv.w * xa.w;
                ar1[di] += tv.x * xb.x + tv.y * xb.y + tv.z * xb.z + tv.w * xb.w;
                ac0[qk * 4 + 0] += tv.x * xa.x;
                ac0[qk * 4 + 1] += tv.y * xa.y;
                ac0[qk * 4 + 2] += tv.z * xa.z;
                ac0[qk * 4 + 3] += tv.w * xa.w;
                ac1[qk * 4 + 0] += tv.x * xb.x;
                ac1[qk * 4 + 1] += tv.y * xb.y;
                ac1[qk * 4 + 2] += tv.z * xb.z;
                ac1[qk * 4 + 3] += tv.w * xb.w;
            }
        }
    }
    // partial stores: no == tid for (n2,o); fully coalesced (64 consecutive dwords/wave)
    int no0 = n2 * CO + o;
    int no1 = (n2 + 8) * CO + o;
    #pragma unroll
    for (int d = 0; d < 16; ++d) {
        rowsP[((size_t)tk * H + I + d) * NO + no0] = ar0[d];
        rowsP[((size_t)tk * H + I + d) * NO + no1] = ar1[d];
        colsP[((size_t)ti * H + K + d) * NO + no0] = ac0[d];
        colsP[((size_t)ti * H + K + d) * NO + no1] = ac1[d];
    }
}

// ---------------- K_reduce: sum 25 strips -> rows2[i][no], cols2[j][no] ----------------
// Reads and writes fully coalesced (no fastest).
__global__ __launch_bounds__(256) void k_reduce(const float* __restrict__ rowsP,
        const float* __restrict__ colsP, float* __restrict__ rows2, float* __restrict__ cols2)
{
    int idx = blockIdx.x * 256 + threadIdx.x;   // 204800 total, grid exact
    int no = idx & (NO - 1);
    int i  = idx >> 9;
    float s = 0.f, t = 0.f;
    #pragma unroll
    for (int k = 0; k < NS; ++k) {
        s += rowsP[((size_t)k * H + i) * NO + no];
        t += colsP[((size_t)k * H + i) * NO + no];
    }
    rows2[(size_t)i * NO + no] = s;
    cols2[(size_t)i * NO + no] = t;
}

// ---------------- K3: final output ----------------
// 16x16 spatial tile, 256 threads (4 waves, o = wave id), X staged in two 8-n halves.
// LDS 36 KB -> 4 blocks/CU -> single dispatch round. rows2/cols2 are [i][no] layout
// (tiny, L2-hot -- strided staging reads are latency-hidden).
#define TS 16
__global__ __launch_bounds__(256, 4) void k_out(const float* __restrict__ x,
        const float* __restrict__ L, const float* __restrict__ bias,
        const float* __restrict__ rows2, const float* __restrict__ cols2,
        float* __restrict__ out)
{
    __shared__ __align__(16) float Xl[8 * CI * TS * TS];   // 32 KB [n'][c][ii][jj]
    __shared__ __align__(16) float rT[8 * 4 * TS];         // 2 KB  [n'][oo][ii]
    __shared__ __align__(16) float cT[8 * 4 * TS];         // 2 KB  [n'][oo][jj]
    int b = blockIdx.x;
    int ti = b / 25, tj = b % 25;
    int i0 = ti * TS, j0 = tj * TS;
    int tid = threadIdx.x;

    int o  = tid >> 6;             // 0..3 (wave id)
    int u  = tid & 63;
    int ii = u >> 2, jq = u & 3;
    const float4* x4  = (const float4*)x;
    const float4* L4  = (const float4*)L;
    const float4* cT4 = (const float4*)cT;
    float4* Xl4  = (float4*)Xl;
    float4* out4 = (float4*)out;

    for (int nh = 0; nh < 2; ++nh) {
        if (nh) __syncthreads();           // all nh=0 readers done before Xl overwrite
        for (int e = tid; e < 8 * CI * TS * 4; e += 256) {   // 2048 float4 = 32 KB
            int q   = e & 3;
            int iiw = (e >> 2) & 15;
            int nc  = nh * (8 * CI) + (e >> 6);   // global n*CI+c
            Xl4[e] = x4[(size_t)(nc * H + i0 + iiw) * 100 + tj * 4 + q];
        }
        for (int os = 0; os < 8; ++os) {
            int og = os * 4 + o;
            float4 T4[CI];
            #pragma unroll
            for (int c = 0; c < CI; ++c) {
                float4 Li = L4[(og * CI + c) * H + i0 + ii];
                float4 La = L4[(og * CI + c) * H + j0 + jq * 4 + 0];
                float4 Lb = L4[(og * CI + c) * H + j0 + jq * 4 + 1];
                float4 Lc = L4[(og * CI + c) * H + j0 + jq * 4 + 2];
                float4 Ld = L4[(og * CI + c) * H + j0 + jq * 4 + 3];
                T4[c].x = Li.x * La.x + Li.y * La.y + Li.z * La.z + Li.w * La.w;
                T4[c].y = Li.x * Lb.x + Li.y * Lb.y + Li.z * Lb.z + Li.w * Lb.w;
                T4[c].z = Li.x * Lc.x + Li.y * Lc.y + Li.z * Lc.z + Li.w * Lc.w;
                T4[c].w = Li.x * Ld.x + Li.y * Ld.y + Li.z * Ld.z + Li.w * Ld.w;
            }
            float bo = bias[og];

            __syncthreads();   // covers Xl staging (os==0) and prev rT/cT readers
            for (int e = tid; e < 8 * 4 * TS; e += 256) {    // 512 elements
                int iw = e & 15;
                int oo = (e >> 4) & 3;
                int np = e >> 6;                  // 0..7
                int n  = nh * 8 + np;
                rT[e] = rows2[(size_t)(i0 + iw) * NO + n * CO + os * 4 + oo];
                cT[e] = cols2[(size_t)(j0 + iw) * NO + n * CO + os * 4 + oo];
            }
            __syncthreads();

            for (int np = 0; np < 8; ++np) {
                float ra  = rT[(np * 4 + o) * TS + ii] + bo;
                float4 ca = cT4[(np * 4 + o) * 4 + jq];
                float4 acc;
                acc.x = ra + ca.x; acc.y = ra + ca.y; acc.z = ra + ca.z; acc.w = ra + ca.w;
                #pragma unroll
                for (int c = 0; c < CI; ++c) {
                    float4 xv = Xl4[((np * CI + c) * TS + ii) * 4 + jq];
                    acc.x -= xv.x * T4[c].x;
                    acc.y -= xv.y * T4[c].y;
                    acc.z -= xv.z * T4[c].z;
                    acc.w -= xv.w * T4[c].w;
                }
                int n = nh * 8 + np;
                out4[((size_t)(n * CO + og) * H + i0 + ii) * 100 + tj * 4 + jq] = acc;
            }
        }
    }
}

extern "C" void kernel_launch(void* const* d_in, const int* in_sizes, int n_in,
                              void* d_out, int out_size, void* d_ws, size_t ws_size,
                              hipStream_t stream) {
    const float* x    = (const float*)d_in[0];
    const float* L    = (const float*)d_in[1];
    const float* bias = (const float*)d_in[2];
    float* out = (float*)d_out;
    char* ws = (char*)d_ws;

    size_t rcP_bytes = (size_t)NS * H * NO * sizeof(float);   // 20,480,000
    size_t rc_bytes  = (size_t)H * NO * sizeof(float);        //    819,200

    float* rowsP = (float*)ws;
    float* colsP = (float*)(ws + rcP_bytes);
    float* rows2 = (float*)(ws + 2 * rcP_bytes);
    float* cols2 = (float*)(ws + 2 * rcP_bytes + rc_bytes);
    (void)ws_size;

    k_rc<<<NS * NS, 256, 0, stream>>>(x, L, rowsP, colsP);
    k_reduce<<<(H * NO) / 256, 256, 0, stream>>>(rowsP, colsP, rows2, cols2);
    k_out<<<625, 256, 0, stream>>>(x, L, bias, rows2, cols2, out);
}

// Round 3
// 549.027 us; speedup vs baseline: 1.1734x; 1.1734x over previous
//
#include <hip/hip_runtime.h>

#define H  400
#define NB 16
#define CI 4
#define CO 32
#define NO (NB * CO)     // 512

// ---------------- K1: transpose each 400x400 plane of X into XT ----------------
// 80x80 tiles, float4 global loads AND stores. 64 nc-planes * 25 tiles = 1600 blocks.
#define TT 80
__global__ __launch_bounds__(256) void k_transpose(const float* __restrict__ x,
                                                   float* __restrict__ xt) {
    __shared__ float tile[TT][TT + 5];   // pad 85: store-phase stride 4*85%32=21 (coprime w/ 32)
    int b = blockIdx.x;
    int tj = b % 5;
    int ti = (b / 5) % 5;
    int nc = b / 25;
    const float* src = x + (size_t)nc * H * H;
    float* dst = xt + (size_t)nc * H * H;
    int i0 = ti * TT, j0 = tj * TT;
    for (int e = threadIdx.x; e < TT * 20; e += 256) {
        int r = e / 20, q = e % 20;
        float4 v = ((const float4*)(src + (size_t)(i0 + r) * H + j0))[q];
        tile[r][q * 4 + 0] = v.x; tile[r][q * 4 + 1] = v.y;
        tile[r][q * 4 + 2] = v.z; tile[r][q * 4 + 3] = v.w;
    }
    __syncthreads();
    for (int e = threadIdx.x; e < TT * 20; e += 256) {
        int r = e / 20, q = e % 20;
        float4 v;
        v.x = tile[q * 4 + 0][r]; v.y = tile[q * 4 + 1][r];
        v.z = tile[q * 4 + 2][r]; v.w = tile[q * 4 + 3][r];
        ((float4*)(dst + (size_t)(j0 + r) * H + i0))[q] = v;
    }
}

// ---------------- K2: partial rows/cols, k-split x5 (proven ~78us with K1) ----------------
#define KC 40
#define KSPLIT 5
__global__ __launch_bounds__(256) void k_rowscols(const float* __restrict__ x,
        const float* __restrict__ xt, const float* __restrict__ L,
        float* __restrict__ rowsP, float* __restrict__ colsP)
{
    __shared__ __align__(16) float4 Lm[CO * CI];      // L[o,c,m,:]
    __shared__ __align__(16) float Xr[NB * CI * KC];
    __shared__ __align__(16) float Xc[NB * CI * KC];
    __shared__ __align__(16) float Tr[CO * 164];      // o*164 + c*KC + k
    int b = blockIdx.x;
    int m  = b / KSPLIT;
    int ks = b % KSPLIT;
    int tid = threadIdx.x;
    const float4* L4 = (const float4*)L;
    if (tid < CO * CI) Lm[tid] = L4[tid * H + m];

    int o  = tid & 31;
    int n0 = tid >> 5;     // 0..7
    float ar0 = 0.f, ar1 = 0.f, ac0 = 0.f, ac1 = 0.f;

    for (int ch = 0; ch < 2; ++ch) {
        int k0 = ks * 80 + ch * KC;
        __syncthreads();
        for (int e = tid; e < NB * CI * KC / 4; e += 256) {   // 640 float4s
            int q  = e % 10;
            int nc = e / 10;
            ((float4*)Xr)[e] = *(const float4*)(x  + (size_t)(nc * H + m) * H + k0 + q * 4);
            ((float4*)Xc)[e] = *(const float4*)(xt + (size_t)(nc * H + m) * H + k0 + q * 4);
        }
        for (int e = tid; e < CO * CI * KC; e += 256) {       // 5120
            int k  = e % KC;
            int oc = e / KC;
            float4 lv = L4[oc * H + k0 + k];
            float4 lm = Lm[oc];
            Tr[(oc >> 2) * 164 + (oc & 3) * KC + k] =
                lv.x * lm.x + lv.y * lm.y + lv.z * lm.z + lv.w * lm.w;
        }
        __syncthreads();
        #pragma unroll
        for (int c = 0; c < CI; ++c) {
            const float4* trp = (const float4*)(Tr + o * 164 + c * KC);
            const float4* pr0 = (const float4*)(Xr + (n0 * CI + c) * KC);
            const float4* pr1 = (const float4*)(Xr + ((n0 + 8) * CI + c) * KC);
            const float4* pc0 = (const float4*)(Xc + (n0 * CI + c) * KC);
            const float4* pc1 = (const float4*)(Xc + ((n0 + 8) * CI + c) * KC);
            #pragma unroll
            for (int q = 0; q < KC / 4; ++q) {
                float4 tv = trp[q];
                float4 a  = pr0[q];
                float4 bb = pr1[q];
                float4 cc = pc0[q];
                float4 dd = pc1[q];
                ar0 += tv.x * a.x  + tv.y * a.y  + tv.z * a.z  + tv.w * a.w;
                ar1 += tv.x * bb.x + tv.y * bb.y + tv.z * bb.z + tv.w * bb.w;
                ac0 += tv.x * cc.x + tv.y * cc.y + tv.z * cc.z + tv.w * cc.w;
                ac1 += tv.x * dd.x + tv.y * dd.y + tv.z * dd.z + tv.w * dd.w;
            }
        }
    }
    // slot = n*CO + o: for ar0 slot == tid, for ar1 slot == tid + 256.
    size_t base = ((size_t)ks * H + m) * NO;
    rowsP[base + tid]       = ar0;
    rowsP[base + 256 + tid] = ar1;
    colsP[base + tid]       = ac0;
    colsP[base + 256 + tid] = ac1;
}

// ---------------- K2b: reduce 5 partials -> rows2[m][no], cols2[m][no] ----------------
__global__ __launch_bounds__(256) void k_reduce(const float* __restrict__ rowsP,
        const float* __restrict__ colsP, float* __restrict__ rows2, float* __restrict__ cols2)
{
    int idx = blockIdx.x * 256 + threadIdx.x;   // 204800 total, grid exact
    int no = idx & (NO - 1);
    int m  = idx >> 9;
    float s = 0.f, t = 0.f;
    #pragma unroll
    for (int k = 0; k < KSPLIT; ++k) {
        s += rowsP[((size_t)k * H + m) * NO + no];
        t += colsP[((size_t)k * H + m) * NO + no];
    }
    rows2[(size_t)m * NO + no] = s;
    cols2[(size_t)m * NO + no] = t;
}

// ---------------- K3: final output, X-in-registers / T-in-LDS ----------------
// Thread = (n = tid>>4, ii = tid&15); holds X[n, 0..3c, i0+ii, j0..j0+15] in 64 VGPRs
// for the whole kernel. Per os-round (4 og): stage 32 L rows to LDS (2 ld/thread),
// cooperatively build T-tile in LDS (stride-20 rows: main reads are 16-distinct-addr,
// 2 per bank-quad), emit 4 og x 16 floats from registers. LDS 36KB -> 4 blocks/CU.
#define TSP 20                       // padded T row stride (floats): ii*20 mod 32 spreads banks
#define TS_OG (CI * 16 * TSP)        // 1280 floats per og'
__global__ __launch_bounds__(256, 4) void k_out(const float* __restrict__ x,
        const float* __restrict__ L, const float* __restrict__ bias,
        const float* __restrict__ rows2, const float* __restrict__ cols2,
        float* __restrict__ out)
{
    __shared__ __align__(16) float4 Lsi[4 * CI * 16];   // [og'][c][r]   4 KB
    __shared__ __align__(16) float4 Lsj[4 * CI * 16];   //               4 KB
    __shared__ __align__(16) float  Ts[4 * TS_OG];      // [og'][c][ii][TSP] 20 KB
    __shared__ __align__(16) float  rT[4 * NB * 16];    // [og'][n][ii]  4 KB
    __shared__ __align__(16) float  cT[4 * NB * 16];    // [og'][n][jj]  4 KB
    int b = blockIdx.x;
    int ti = b / 25, tj = b % 25;
    int i0 = ti * 16, j0 = tj * 16;
    int tid = threadIdx.x;
    int n  = tid >> 4;        // 0..15
    int ii = tid & 15;        // 0..15
    const float4* x4  = (const float4*)x;
    const float4* L4  = (const float4*)L;
    const float4* cT4 = (const float4*)cT;
    float4* out4 = (float4*)out;

    // X tile slice -> registers (read once; coalesced 64B/thread)
    float4 Xr[CI][4];
    #pragma unroll
    for (int c = 0; c < CI; ++c)
        #pragma unroll
        for (int q = 0; q < 4; ++q)
            Xr[c][q] = x4[((size_t)(n * CI + c) * H + i0 + ii) * 100 + tj * 4 + q];

    for (int os = 0; os < 8; ++os) {
        __syncthreads();   // previous round's readers done with Ls/Ts/rT/cT
        {   // stage L rows: 256 threads cover 4og' x 4c x 16r exactly, i-side + j-side
            int r   = tid & 15;
            int cg  = (tid >> 4) & 3;
            int og_ = tid >> 6;
            size_t lrow = (size_t)((os * 4 + og_) * CI + cg) * H;
            Lsi[(og_ * CI + cg) * 16 + r] = L4[lrow + i0 + r];
            Lsj[(og_ * CI + cg) * 16 + r] = L4[lrow + j0 + r];
        }
        for (int e = tid; e < 1024; e += 256) {   // rows/cols slices (L2-hot, small)
            int iw  = e & 15;
            int og_ = (e >> 4) & 3;
            int nn  = e >> 6;
            rT[(og_ * NB + nn) * 16 + iw] = rows2[(size_t)(i0 + iw) * NO + nn * CO + os * 4 + og_];
            cT[(og_ * NB + nn) * 16 + iw] = cols2[(size_t)(j0 + iw) * NO + nn * CO + os * 4 + og_];
        }
        __syncthreads();
        {   // T-tile: thread -> (og', c, ii), computes 16 jj via rank-4 dots from LDS
            int iw  = tid & 15;
            int cc  = (tid >> 4) & 3;
            int og_ = tid >> 6;
            float4 Li = Lsi[(og_ * CI + cc) * 16 + iw];
            float* tsrow = Ts + og_ * TS_OG + cc * (16 * TSP) + iw * TSP;
            #pragma unroll
            for (int q = 0; q < 4; ++q) {
                float4 t;
                #pragma unroll
                for (int w = 0; w < 4; ++w) {
                    float4 Lj = Lsj[(og_ * CI + cc) * 16 + q * 4 + w];
                    ((float*)&t)[w] = Li.x * Lj.x + Li.y * Lj.y + Li.z * Lj.z + Li.w * Lj.w;
                }
                *(float4*)(tsrow + q * 4) = t;
            }
        }
        __syncthreads();
        // main: 4 og outputs from registers; stores 64B contiguous per thread
        #pragma unroll
        for (int og_ = 0; og_ < 4; ++og_) {
            int og = os * 4 + og_;
            float ra = rT[(og_ * NB + n) * 16 + ii] + bias[og];
            float4 acc[4];
            #pragma unroll
            for (int q = 0; q < 4; ++q) {
                float4 ca = cT4[(og_ * NB + n) * 4 + q];
                acc[q].x = ra + ca.x; acc[q].y = ra + ca.y;
                acc[q].z = ra + ca.z; acc[q].w = ra + ca.w;
            }
            #pragma unroll
            for (int c = 0; c < CI; ++c) {
                const float* tsrow = Ts + og_ * TS_OG + c * (16 * TSP) + ii * TSP;
                #pragma unroll
                for (int q = 0; q < 4; ++q) {
                    float4 tq = *(const float4*)(tsrow + q * 4);
                    acc[q].x -= Xr[c][q].x * tq.x;
                    acc[q].y -= Xr[c][q].y * tq.y;
                    acc[q].z -= Xr[c][q].z * tq.z;
                    acc[q].w -= Xr[c][q].w * tq.w;
                }
            }
            size_t ob = ((size_t)(n * CO + og) * H + i0 + ii) * 100 + tj * 4;
            #pragma unroll
            for (int q = 0; q < 4; ++q) out4[ob + q] = acc[q];
        }
    }
}

extern "C" void kernel_launch(void* const* d_in, const int* in_sizes, int n_in,
                              void* d_out, int out_size, void* d_ws, size_t ws_size,
                              hipStream_t stream) {
    const float* x    = (const float*)d_in[0];
    const float* L    = (const float*)d_in[1];
    const float* bias = (const float*)d_in[2];
    float* out = (float*)d_out;
    char* ws = (char*)d_ws;

    size_t xt_bytes  = (size_t)NB * CI * H * H * sizeof(float);      // 40,960,000
    size_t rc_elems  = (size_t)H * NO;                               // 204,800
    size_t rcP_bytes = (size_t)KSPLIT * rc_elems * sizeof(float);    // 4,096,000
    size_t rc_bytes  = rc_elems * sizeof(float);                     //   819,200

    float* XT    = (float*)ws;
    float* rowsP = (float*)(ws + xt_bytes);
    float* colsP = (float*)(ws + xt_bytes + rcP_bytes);
    float* rows2 = (float*)(ws + xt_bytes + 2 * rcP_bytes);
    float* cols2 = (float*)(ws + xt_bytes + 2 * rcP_bytes + rc_bytes);
    (void)ws_size;

    k_transpose<<<1600, 256, 0, stream>>>(x, XT);
    k_rowscols<<<H * KSPLIT, 256, 0, stream>>>(x, XT, L, rowsP, colsP);
    k_reduce<<<(H * NO) / 256, 256, 0, stream>>>(rowsP, colsP, rows2, cols2);
    k_out<<<625, 256, 0, stream>>>(x, L, bias, rows2, cols2, out);
}

// Round 5
// 506.203 us; speedup vs baseline: 1.2726x; 1.0846x over previous
//
#include <hip/hip_runtime.h>

#define H  400
#define NB 16
#define CI 4
#define CO 32
#define NO (NB * CO)     // 512

// ---------------- K1: transpose each 400x400 plane of X into XT ----------------
// 80x80 tiles, float4 global loads AND stores. 64 nc-planes * 25 tiles = 1600 blocks.
#define TT 80
__global__ __launch_bounds__(256) void k_transpose(const float* __restrict__ x,
                                                   float* __restrict__ xt) {
    __shared__ float tile[TT][TT + 5];   // pad 85: store-phase stride 4*85%32=21 (coprime w/ 32)
    int b = blockIdx.x;
    int tj = b % 5;
    int ti = (b / 5) % 5;
    int nc = b / 25;
    const float* src = x + (size_t)nc * H * H;
    float* dst = xt + (size_t)nc * H * H;
    int i0 = ti * TT, j0 = tj * TT;
    for (int e = threadIdx.x; e < TT * 20; e += 256) {
        int r = e / 20, q = e % 20;
        float4 v = ((const float4*)(src + (size_t)(i0 + r) * H + j0))[q];
        tile[r][q * 4 + 0] = v.x; tile[r][q * 4 + 1] = v.y;
        tile[r][q * 4 + 2] = v.z; tile[r][q * 4 + 3] = v.w;
    }
    __syncthreads();
    for (int e = threadIdx.x; e < TT * 20; e += 256) {
        int r = e / 20, q = e % 20;
        float4 v;
        v.x = tile[q * 4 + 0][r]; v.y = tile[q * 4 + 1][r];
        v.z = tile[q * 4 + 2][r]; v.w = tile[q * 4 + 3][r];
        ((float4*)(dst + (size_t)(j0 + r) * H + i0))[q] = v;
    }
}

// ---------------- K2: partial rows/cols, k-split x5 ----------------
// Tr layout [c][q][o] float4: hot-loop read = 32 lanes x consecutive 16B = 512B
// contiguous, conflict-free (was 4-way). T-writer emits one float4 per thread at
// consecutive slots -> ds_write_b128 conflict-free (scalar version was 16-way).
// Chunked XCD swizzle: the 5 ks-blocks of each m share an XCD L2 (same X/XT rows).
#define KC 40
#define KSPLIT 5
__global__ __launch_bounds__(256) void k_rowscols(const float* __restrict__ x,
        const float* __restrict__ xt, const float* __restrict__ L,
        float* __restrict__ rowsP, float* __restrict__ colsP)
{
    __shared__ __align__(16) float4 Lm[CO * CI];      // L[o,c,m,:]
    __shared__ __align__(16) float Xr[NB * CI * KC];
    __shared__ __align__(16) float Xc[NB * CI * KC];
    __shared__ __align__(16) float Tr[CO * CI * KC];  // float4 slot (c*10+q)*32 + o
    int hw = blockIdx.x;                 // 2000 = 8*250: chunked XCD swizzle (bijective)
    int b  = (hw & 7) * 250 + (hw >> 3);
    int m  = b / KSPLIT;
    int ks = b % KSPLIT;
    int tid = threadIdx.x;
    const float4* L4 = (const float4*)L;
    if (tid < CO * CI) Lm[tid] = L4[tid * H + m];

    int o  = tid & 31;
    int n0 = tid >> 5;     // 0..7
    float ar0 = 0.f, ar1 = 0.f, ac0 = 0.f, ac1 = 0.f;

    for (int ch = 0; ch < 2; ++ch) {
        int k0 = ks * 80 + ch * KC;
        __syncthreads();
        for (int e = tid; e < NB * CI * KC / 4; e += 256) {   // 640 float4s
            int q  = e % 10;
            int nc = e / 10;
            ((float4*)Xr)[e] = *(const float4*)(x  + (size_t)(nc * H + m) * H + k0 + q * 4);
            ((float4*)Xc)[e] = *(const float4*)(xt + (size_t)(nc * H + m) * H + k0 + q * 4);
        }
        // T-writer: 1280 float4 slots; thread -> (oo fastest) so b128 stores are
        // lane-consecutive 16B (conflict-free).
        for (int e = tid; e < CO * CI * KC / 4; e += 256) {
            int oo = e & 31;
            int t  = e >> 5;        // 0..39
            int q  = t % 10;
            int cc = t / 10;
            int oc = oo * CI + cc;
            float4 lm = Lm[oc];
            float4 t4;
            #pragma unroll
            for (int w = 0; w < 4; ++w) {
                float4 lv = L4[oc * H + k0 + q * 4 + w];
                ((float*)&t4)[w] = lv.x * lm.x + lv.y * lm.y + lv.z * lm.z + lv.w * lm.w;
            }
            ((float4*)Tr)[(cc * 10 + q) * 32 + oo] = t4;
        }
        __syncthreads();
        #pragma unroll
        for (int c = 0; c < CI; ++c) {
            const float4* pr0 = (const float4*)(Xr + (n0 * CI + c) * KC);
            const float4* pr1 = (const float4*)(Xr + ((n0 + 8) * CI + c) * KC);
            const float4* pc0 = (const float4*)(Xc + (n0 * CI + c) * KC);
            const float4* pc1 = (const float4*)(Xc + ((n0 + 8) * CI + c) * KC);
            #pragma unroll
            for (int q = 0; q < KC / 4; ++q) {
                float4 tv = ((const float4*)Tr)[(c * 10 + q) * 32 + o];
                float4 a  = pr0[q];
                float4 bb = pr1[q];
                float4 cc = pc0[q];
                float4 dd = pc1[q];
                ar0 += tv.x * a.x  + tv.y * a.y  + tv.z * a.z  + tv.w * a.w;
                ar1 += tv.x * bb.x + tv.y * bb.y + tv.z * bb.z + tv.w * bb.w;
                ac0 += tv.x * cc.x + tv.y * cc.y + tv.z * cc.z + tv.w * cc.w;
                ac1 += tv.x * dd.x + tv.y * dd.y + tv.z * dd.z + tv.w * dd.w;
            }
        }
    }
    // slot = n*CO + o: for ar0 slot == tid, for ar1 slot == tid + 256.
    size_t base = ((size_t)ks * H + m) * NO;
    rowsP[base + tid]       = ar0;
    rowsP[base + 256 + tid] = ar1;
    colsP[base + tid]       = ac0;
    colsP[base + 256 + tid] = ac1;
}

// ---------------- K2b: reduce 5 partials AND transpose -> rows2T[no][m] ----------------
// LDS tile-transpose: global reads coalesced (no fastest), global writes 64B-chunked
// (m fastest). Output layout [no][m] makes k_out's rT/cT staging contiguous
// (was a 2KB-stride 4B scatter: 64 L2 sectors per wave-instr).
__global__ __launch_bounds__(256) void k_reduce_t(const float* __restrict__ rowsP,
        const float* __restrict__ colsP, float* __restrict__ rows2T, float* __restrict__ cols2T)
{
    __shared__ float Lr[16][257];
    __shared__ float Lc[16][257];
    int b  = blockIdx.x;          // 50 = 25 m-tiles * 2 no-halves
    int mt = b % 25, nt = b / 25;
    int tid = threadIdx.x;
    #pragma unroll
    for (int mm = 0; mm < 16; ++mm) {
        float s = 0.f, t = 0.f;
        #pragma unroll
        for (int ks = 0; ks < KSPLIT; ++ks) {
            s += rowsP[((size_t)ks * H + mt * 16 + mm) * NO + nt * 256 + tid];
            t += colsP[((size_t)ks * H + mt * 16 + mm) * NO + nt * 256 + tid];
        }
        Lr[mm][tid] = s;
        Lc[mm][tid] = t;
    }
    __syncthreads();
    for (int e = tid; e < 16 * 256; e += 256) {
        int m_  = e & 15;
        int no_ = e >> 4;
        rows2T[(size_t)(nt * 256 + no_) * H + mt * 16 + m_] = Lr[m_][no_];
        cols2T[(size_t)(nt * 256 + no_) * H + mt * 16 + m_] = Lc[m_][no_];
    }
}

// ---------------- K3: final output (round-1 proven structure) ----------------
// 16x16 spatial tile, 256 threads (4 waves, o = wave id), X staged in two 8-n halves.
// Changes vs round-1: (a) rT/cT staging reads the [no][m] layout -> 64B-contiguous
// per 16 lanes; (b) chunked XCD swizzle -> adjacent tj tiles (which split 128B output
// lines and share rows2T/x rows) land on the same XCD L2.
#define TS 16
__global__ __launch_bounds__(256, 4) void k_out(const float* __restrict__ x,
        const float* __restrict__ L, const float* __restrict__ bias,
        const float* __restrict__ rows2T, const float* __restrict__ cols2T,
        float* __restrict__ out)
{
    __shared__ __align__(16) float Xl[8 * CI * TS * TS];   // 32 KB [n'][c][ii][jj]
    __shared__ __align__(16) float rT[8 * 4 * TS];         // 2 KB  [n'][oo][ii]
    __shared__ __align__(16) float cT[8 * 4 * TS];         // 2 KB  [n'][oo][jj]
    int hw = blockIdx.x;               // 625 = 79 + 7*78: chunked XCD swizzle (bijective)
    int xcd = hw & 7, pos = hw >> 3;
    int b = (xcd == 0) ? pos : (79 + (xcd - 1) * 78 + pos);
    int ti = b / 25, tj = b % 25;
    int i0 = ti * TS, j0 = tj * TS;
    int tid = threadIdx.x;

    int o  = tid >> 6;             // 0..3 (wave id)
    int u  = tid & 63;
    int ii = u >> 2, jq = u & 3;
    const float4* x4  = (const float4*)x;
    const float4* L4  = (const float4*)L;
    const float4* cT4 = (const float4*)cT;
    float4* Xl4  = (float4*)Xl;
    float4* out4 = (float4*)out;

    for (int nh = 0; nh < 2; ++nh) {
        if (nh) __syncthreads();           // all nh=0 readers done before Xl overwrite
        for (int e = tid; e < 8 * CI * TS * 4; e += 256) {   // 2048 float4 = 32 KB
            int q   = e & 3;
            int iiw = (e >> 2) & 15;
            int nc  = nh * (8 * CI) + (e >> 6);   // global n*CI+c
            Xl4[e] = x4[(size_t)(nc * H + i0 + iiw) * 100 + tj * 4 + q];
        }
        for (int os = 0; os < 8; ++os) {
            int og = os * 4 + o;
            float4 T4[CI];
            #pragma unroll
            for (int c = 0; c < CI; ++c) {
                float4 Li = L4[(og * CI + c) * H + i0 + ii];
                float4 La = L4[(og * CI + c) * H + j0 + jq * 4 + 0];
                float4 Lb = L4[(og * CI + c) * H + j0 + jq * 4 + 1];
                float4 Lc = L4[(og * CI + c) * H + j0 + jq * 4 + 2];
                float4 Ld = L4[(og * CI + c) * H + j0 + jq * 4 + 3];
                T4[c].x = Li.x * La.x + Li.y * La.y + Li.z * La.z + Li.w * La.w;
                T4[c].y = Li.x * Lb.x + Li.y * Lb.y + Li.z * Lb.z + Li.w * Lb.w;
                T4[c].z = Li.x * Lc.x + Li.y * Lc.y + Li.z * Lc.z + Li.w * Lc.w;
                T4[c].w = Li.x * Ld.x + Li.y * Ld.y + Li.z * Ld.z + Li.w * Ld.w;
            }
            float bo = bias[og];

            __syncthreads();   // covers Xl staging (os==0) and prev rT/cT readers
            for (int e = tid; e < 8 * 4 * TS; e += 256) {    // 512 elements
                int iw = e & 15;
                int oo = (e >> 4) & 3;
                int np = e >> 6;                  // 0..7
                int n  = nh * 8 + np;
                size_t no = (size_t)(n * CO + os * 4 + oo);
                rT[e] = rows2T[no * H + i0 + iw];
                cT[e] = cols2T[no * H + j0 + iw];
            }
            __syncthreads();

            for (int np = 0; np < 8; ++np) {
                float ra  = rT[(np * 4 + o) * TS + ii] + bo;
                float4 ca = cT4[(np * 4 + o) * 4 + jq];
                float4 acc;
                acc.x = ra + ca.x; acc.y = ra + ca.y; acc.z = ra + ca.z; acc.w = ra + ca.w;
                #pragma unroll
                for (int c = 0; c < CI; ++c) {
                    float4 xv = Xl4[((np * CI + c) * TS + ii) * 4 + jq];
                    acc.x -= xv.x * T4[c].x;
                    acc.y -= xv.y * T4[c].y;
                    acc.z -= xv.z * T4[c].z;
                    acc.w -= xv.w * T4[c].w;
                }
                int n = nh * 8 + np;
                out4[((size_t)(n * CO + og) * H + i0 + ii) * 100 + tj * 4 + jq] = acc;
            }
        }
    }
}

extern "C" void kernel_launch(void* const* d_in, const int* in_sizes, int n_in,
                              void* d_out, int out_size, void* d_ws, size_t ws_size,
                              hipStream_t stream) {
    const float* x    = (const float*)d_in[0];
    const float* L    = (const float*)d_in[1];
    const float* bias = (const float*)d_in[2];
    float* out = (float*)d_out;
    char* ws = (char*)d_ws;

    size_t xt_bytes  = (size_t)NB * CI * H * H * sizeof(float);      // 40,960,000
    size_t rc_elems  = (size_t)H * NO;                               // 204,800
    size_t rcP_bytes = (size_t)KSPLIT * rc_elems * sizeof(float);    // 4,096,000
    size_t rc_bytes  = rc_elems * sizeof(float);                     //   819,200

    float* XT     = (float*)ws;
    float* rowsP  = (float*)(ws + xt_bytes);
    float* colsP  = (float*)(ws + xt_bytes + rcP_bytes);
    float* rows2T = (float*)(ws + xt_bytes + 2 * rcP_bytes);
    float* cols2T = (float*)(ws + xt_bytes + 2 * rcP_bytes + rc_bytes);
    (void)ws_size;

    k_transpose<<<1600, 256, 0, stream>>>(x, XT);
    k_rowscols<<<H * KSPLIT, 256, 0, stream>>>(x, XT, L, rowsP, colsP);
    k_reduce_t<<<50, 256, 0, stream>>>(rowsP, colsP, rows2T, cols2T);
    k_out<<<625, 256, 0, stream>>>(x, L, bias, rows2T, cols2T, out);
}